// Round 8
// baseline (395.331 us; speedup 1.0000x reference)
//
#include <hip/hip_runtime.h>
#include <math.h>

// Problem constants (match reference)
#define B_TOK 16384
#define H_DIM 2048
#define NE    8
#define TOPK  2
#define HFD   512

#define BK 32
#define NKSTEP (H_DIM / BK)   // 64
#define PTMAX 129             // covers worst-case expert count (16512/128)

// Workspace layout (bytes)
static constexpr size_t OFF_COUNTS = 0;           // 32 B
static constexpr size_t OFF_CBASE  = 128;         // cbase[8] + cpad[8]
static constexpr size_t OFF_BUCKET = 1024;        // 512 KB
static constexpr size_t OFF_WSLOT  = 525312;      // 128 KB
static constexpr size_t OFF_ROUTE  = 656384;      // 64 KB
static constexpr size_t OFF_INV    = 721920;      // 128 KB
static constexpr size_t OFF_P      = 860160;      // 33792 floats
static constexpr size_t OFF_WGT    = 1u << 20;    // 8 replicas x 64 KB = 512 KB
static constexpr size_t OFF_W1H    = 2u << 20;    // 16 MB
static constexpr size_t OFF_XGT    = 19922944;    // 33792 rows * 4 KB = 132 MB

typedef short bfrag __attribute__((ext_vector_type(8)));   // 8 bf16 (4 VGPR)
typedef float facc  __attribute__((ext_vector_type(16)));  // 32x32 accum

__device__ inline unsigned short f2bf(float f) {
    union { float f; unsigned u; } v; v.f = f;
    unsigned r = v.u + 0x7FFFu + ((v.u >> 16) & 1u);
    return (unsigned short)(r >> 16);
}
__device__ inline unsigned pack2(float lo, float hi) {
    return (unsigned)f2bf(lo) | ((unsigned)f2bf(hi) << 16);
}

__device__ __forceinline__ void gload_lds16(const void* g, void* l) {
    __builtin_amdgcn_global_load_lds(
        (const __attribute__((address_space(1))) unsigned int*)g,
        (__attribute__((address_space(3))) unsigned int*)l, 16, 0, 0);
}

// ---------------------------------------------------------------------------
// Transpose gate weights: Wg [H][E] -> 8 replicas of WgT [E][H].
// ---------------------------------------------------------------------------
__global__ __launch_bounds__(256)
void wg_transpose_kernel(const float* __restrict__ Wg,
                         float* __restrict__ WgT)
{
    const int t = threadIdx.x;
    #pragma unroll
    for (int rep = 0; rep < H_DIM / 256; ++rep) {
        const int h = rep * 256 + t;
        const float4 a = *reinterpret_cast<const float4*>(Wg + (size_t)h * NE);
        const float4 b = *reinterpret_cast<const float4*>(Wg + (size_t)h * NE + 4);
        #pragma unroll
        for (int rr = 0; rr < 8; ++rr) {
            float* W = WgT + (size_t)rr * (NE * H_DIM);
            W[0 * H_DIM + h] = a.x;  W[1 * H_DIM + h] = a.y;
            W[2 * H_DIM + h] = a.z;  W[3 * H_DIM + h] = a.w;
            W[4 * H_DIM + h] = b.x;  W[5 * H_DIM + h] = b.y;
            W[6 * H_DIM + h] = b.z;  W[7 * H_DIM + h] = b.w;
        }
    }
}

// ---------------------------------------------------------------------------
// Prep W1: [E][H][HF] fp32 -> per-(e, f-half) k-slot-major bf16 images:
//   W1h[(e*2+mt)*64 + kstep][slot(4)][f'(256)][j(8)]  (16 KB per image)
// ---------------------------------------------------------------------------
__global__ __launch_bounds__(256)
void prep_w1_kernel(const float* __restrict__ W1,
                    unsigned short* __restrict__ W1h)
{
    const int blk   = blockIdx.x;       // e*64 + kstep
    const int e     = blk >> 6;
    const int kstep = blk & 63;
    const int tid   = threadIdx.x;

    const float* src = W1 + ((size_t)e * H_DIM + kstep * BK) * HFD;

    #pragma unroll
    for (int s = 0; s < 4; ++s) {
        #pragma unroll
        for (int mt = 0; mt < 2; ++mt) {
            const int f = mt * 256 + tid;
            float v[8];
            #pragma unroll
            for (int j = 0; j < 8; ++j)
                v[j] = src[(size_t)(s * 8 + j) * HFD + f];   // coalesced
            uint4 p;
            p.x = pack2(v[0], v[1]); p.y = pack2(v[2], v[3]);
            p.z = pack2(v[4], v[5]); p.w = pack2(v[6], v[7]);
            *reinterpret_cast<uint4*>(
                W1h + ((size_t)((e * 2 + mt) * 64 + kstep)) * 8192
                    + (s * 256 + tid) * 8) = p;
        }
    }
}

// ---------------------------------------------------------------------------
// Gate logits: 256 blocks x 64 tokens. WgT staged ONCE per block into LDS
// (kills the L2 hot-spot of 16384 waves re-streaming the same 64 KB).
// Each wave: 16 tokens in 4 passes of 4 (W read amortized 4x).
// ---------------------------------------------------------------------------
__global__ __launch_bounds__(256)
void gate_logits_kernel(const float* __restrict__ x,
                        const float* __restrict__ WgT,
                        const float* __restrict__ bg,
                        float* __restrict__ out_logits,
                        float* __restrict__ wslot,
                        int*   __restrict__ route)
{
    __shared__ float Wlds[NE * H_DIM];   // 64 KB

    const int tid = threadIdx.x;
    const float* Wsrc = WgT + (size_t)(blockIdx.x & 7) * (NE * H_DIM);
    #pragma unroll
    for (int i = 0; i < (NE * H_DIM) / (256 * 4); ++i) {
        const int idx = (i * 256 + tid) * 4;
        *reinterpret_cast<float4*>(&Wlds[idx]) =
            *reinterpret_cast<const float4*>(Wsrc + idx);
    }
    __syncthreads();

    const int w = tid >> 6, l = tid & 63;
    const int tbase = blockIdx.x * 64 + w * 16;

    for (int pass = 0; pass < 4; ++pass) {
        const int t0 = tbase + pass * 4;
        float acc[4][NE];
        #pragma unroll
        for (int j = 0; j < 4; ++j)
            #pragma unroll
            for (int e = 0; e < NE; ++e) acc[j][e] = 0.f;

        for (int i = 0; i < 8; ++i) {
            const int h = i * 256 + 4 * l;
            float4 xv[4];
            #pragma unroll
            for (int j = 0; j < 4; ++j)
                xv[j] = *reinterpret_cast<const float4*>(
                    x + (size_t)(t0 + j) * H_DIM + h);
            #pragma unroll
            for (int e = 0; e < NE; ++e) {
                const float4 wv = *reinterpret_cast<const float4*>(&Wlds[e * H_DIM + h]);
                #pragma unroll
                for (int j = 0; j < 4; ++j)
                    acc[j][e] += xv[j].x * wv.x + xv[j].y * wv.y
                               + xv[j].z * wv.z + xv[j].w * wv.w;
            }
        }

        #pragma unroll
        for (int j = 0; j < 4; ++j)
            #pragma unroll
            for (int e = 0; e < NE; ++e)
                #pragma unroll
                for (int off = 32; off > 0; off >>= 1)
                    acc[j][e] += __shfl_xor(acc[j][e], off, 64);

        if (l == 0) {
            #pragma unroll
            for (int j = 0; j < 4; ++j) {
                const int tok = t0 + j;
                float lg[NE];
                #pragma unroll
                for (int e = 0; e < NE; ++e) lg[e] = acc[j][e] + bg[e];

                float4* lo = reinterpret_cast<float4*>(out_logits + (size_t)tok * NE);
                lo[0] = make_float4(lg[0], lg[1], lg[2], lg[3]);
                lo[1] = make_float4(lg[4], lg[5], lg[6], lg[7]);

                int i0 = 0; float v0 = lg[0];
                #pragma unroll
                for (int e = 1; e < NE; ++e)
                    if (lg[e] > v0) { v0 = lg[e]; i0 = e; }
                int i1 = -1; float v1 = -3.4e38f;
                #pragma unroll
                for (int e = 0; e < NE; ++e)
                    if (e != i0 && lg[e] > v1) { v1 = lg[e]; i1 = e; }

                const float w0 = 1.f / (1.f + expf(v1 - v0));
                wslot[tok * 2]     = w0;
                wslot[tok * 2 + 1] = 1.f - w0;
                route[tok] = i0 | (i1 << 8);
            }
        }
    }
}

// ---------------------------------------------------------------------------
// Route/bucket: LDS-aggregated histogram; 8 global atomics per block.
// ---------------------------------------------------------------------------
__global__ __launch_bounds__(1024)
void route_kernel(const int* __restrict__ route,
                  int* __restrict__ counts,
                  int* __restrict__ bucket)
{
    __shared__ int lcnt[NE];
    __shared__ int lbase[NE];
    const int tid = threadIdx.x;
    const int tok = blockIdx.x * 1024 + tid;

    if (tid < NE) lcnt[tid] = 0;
    __syncthreads();

    const int rt = route[tok];
    const int i0 = rt & 255;
    const int i1 = rt >> 8;
    const int r0 = atomicAdd(&lcnt[i0], 1);
    const int r1 = atomicAdd(&lcnt[i1], 1);
    __syncthreads();

    if (tid < NE) lbase[tid] = atomicAdd(&counts[tid], lcnt[tid]);
    __syncthreads();

    bucket[i0 * B_TOK + lbase[i0] + r0] = tok * 2;
    bucket[i1 * B_TOK + lbase[i1] + r1] = tok * 2 + 1;
}

// ---------------------------------------------------------------------------
// Prefix: cbase[e] = row base; cpad[e] = count padded to 128.
// ---------------------------------------------------------------------------
__global__ void prefix_kernel(const int* __restrict__ counts,
                              int* __restrict__ cbase)
{
    if (threadIdx.x == 0 && blockIdx.x == 0) {
        int acc = 0;
        for (int e = 0; e < NE; ++e) {
            const int cp = ((counts[e] + 127) >> 7) << 7;
            cbase[e]      = acc;
            cbase[NE + e] = cp;
            acc += cp;
        }
    }
}

// ---------------------------------------------------------------------------
// X gather/transpose -> k-slot-major image
//   xgT[cb + pos rows][kstep(64)][slot(4)][pos][j(8)]
// ---------------------------------------------------------------------------
__global__ __launch_bounds__(256)
void xgather_kernel(const float* __restrict__ x,
                    const int* __restrict__ bucket,
                    const int* __restrict__ counts,
                    const int* __restrict__ cbase,
                    unsigned short* __restrict__ xgT,
                    int* __restrict__ inv)
{
    const int e    = blockIdx.x & 7;
    const int tile = blockIdx.x >> 3;
    const int n    = counts[e];
    const int pos0 = tile * 64;
    if (pos0 >= n) return;
    const int cb   = cbase[e];
    const size_t cpad = (size_t)cbase[NE + e];
    const int t = threadIdx.x;

    __shared__ int toks[64];
    __shared__ unsigned short T[8][64][8];

    if (t < 64) {
        const int pos = pos0 + t;
        const int entry = bucket[e * B_TOK + min(pos, n - 1)];
        toks[t] = entry >> 1;
        if (pos < n) inv[entry] = cb + pos;
    }
    __syncthreads();

    const int p = t >> 2;
    const int q = t & 3;
    const float* src = x + (size_t)toks[p] * H_DIM + q * 16;
    unsigned short* dstbase = xgT + (size_t)cb * H_DIM;

    for (int kc = 0; kc < 32; ++kc) {
        const float4 v0 = *reinterpret_cast<const float4*>(src + kc * 64);
        const float4 v1 = *reinterpret_cast<const float4*>(src + kc * 64 + 4);
        const float4 v2 = *reinterpret_cast<const float4*>(src + kc * 64 + 8);
        const float4 v3 = *reinterpret_cast<const float4*>(src + kc * 64 + 12);
        uint4 pa, pb;
        pa.x = pack2(v0.x, v0.y); pa.y = pack2(v0.z, v0.w);
        pa.z = pack2(v1.x, v1.y); pa.w = pack2(v1.z, v1.w);
        pb.x = pack2(v2.x, v2.y); pb.y = pack2(v2.z, v2.w);
        pb.z = pack2(v3.x, v3.y); pb.w = pack2(v3.z, v3.w);
        __syncthreads();
        *reinterpret_cast<uint4*>(&T[q * 2][p][0])     = pa;
        *reinterpret_cast<uint4*>(&T[q * 2 + 1][p][0]) = pb;
        __syncthreads();
        #pragma unroll
        for (int g = 0; g < 2; ++g) {
            const int u   = t + g * 256;
            const int s8  = u >> 6;
            const int pp  = u & 63;
            const int kst = 2 * kc + (s8 >> 2);
            const int sl  = s8 & 3;
            *reinterpret_cast<uint4*>(
                dstbase + ((size_t)(kst * 4 + sl) * cpad + pos0 + pp) * 8) =
                *reinterpret_cast<const uint4*>(&T[s8][pp][0]);
        }
    }
}

// ---------------------------------------------------------------------------
// Expert MFMA: block = (e, f-half mt, 128-pos tile). 512 thr / 8 waves
// (2M x 4N: wave = 128 f x 32 pos, acc 4x f32x16 = 64 VGPR).
// A (16 KB/step, L2-hot) LDS double-buffered via linear global_load_lds.
// B fragments load DIRECTLY to VGPRs from the k-slot-major xgT image
// (two coalesced 512B segments per load) with 1-step reg double-buffer.
// Counted vmcnt(4) + raw barriers; K-loop fully unrolled so all buffer
// indices are static. 33 KB LDS + <=128 VGPR -> 2 blocks/CU co-resident.
// ---------------------------------------------------------------------------
__global__ __launch_bounds__(512, 4)
void expert_mfma_kernel(const unsigned short* __restrict__ xgT,
                        const unsigned short* __restrict__ W1h,
                        const float* __restrict__ b1,
                        const float* __restrict__ W2,
                        const int* __restrict__ counts,
                        const int* __restrict__ cbase,
                        float* __restrict__ P)
{
    const int e  = blockIdx.x & 7;
    const int r  = blockIdx.x >> 3;
    const int mt = r & 1;
    const int pt = r >> 1;
    const int n  = counts[e];
    const int pos0 = pt * 128;
    if (pos0 >= n) return;
    const int nt = min(128, n - pos0);
    const int cb = cbase[e];
    const size_t cpad = (size_t)cbase[NE + e];

    __shared__ unsigned short Abuf[2][8192];   // 2 x 16 KB  [slot4][f'256][8]
    __shared__ float o_part[2][128];

    const int tid = threadIdx.x;
    const int w   = tid >> 6;
    const int l   = tid & 63;
    const int lo5 = l & 31;
    const int hi  = l >> 5;
    const int wm  = w & 1;       // f-group (128 rows)
    const int wn  = w >> 1;      // pos-group (32 cols)

    const unsigned short* Asrc = W1h + (size_t)((e * 2 + mt) * 64) * 8192;
    const bfrag* Bsrc = reinterpret_cast<const bfrag*>(xgT + (size_t)cb * H_DIM);
    const size_t posl = (size_t)pos0 + wn * 32 + lo5;

    facc acc[4];
    #pragma unroll
    for (int m = 0; m < 4; ++m)
        #pragma unroll
        for (int q = 0; q < 16; ++q) acc[m][q] = 0.f;

    bfrag breg[2][2];
    const int aoff = w * 1024 + l * 8;   // shorts: wave w owns 2 x 1KB chunks

    // prologue: step 0 in flight
    gload_lds16(Asrc + aoff,       &Abuf[0][aoff]);
    gload_lds16(Asrc + aoff + 512, &Abuf[0][aoff + 512]);
    breg[0][0] = Bsrc[(size_t)(0 + hi) * cpad + posl];
    breg[0][1] = Bsrc[(size_t)(2 + hi) * cpad + posl];

    #pragma unroll
    for (int kk = 0; kk < NKSTEP; ++kk) {
        const int cur = kk & 1;
        if (kk < NKSTEP - 1) {
            const unsigned short* as = Asrc + (size_t)(kk + 1) * 8192;
            gload_lds16(as + aoff,       &Abuf[cur ^ 1][aoff]);
            gload_lds16(as + aoff + 512, &Abuf[cur ^ 1][aoff + 512]);
            breg[cur ^ 1][0] = Bsrc[(size_t)((kk + 1) * 4 + hi) * cpad + posl];
            breg[cur ^ 1][1] = Bsrc[(size_t)((kk + 1) * 4 + 2 + hi) * cpad + posl];
            asm volatile("s_waitcnt vmcnt(4)" ::: "memory");  // step kk complete
        } else {
            asm volatile("s_waitcnt vmcnt(0)" ::: "memory");
        }
        __builtin_amdgcn_s_barrier();          // Abuf[cur] visible

        #pragma unroll
        for (int ki = 0; ki < 2; ++ki) {
            bfrag a[4];
            #pragma unroll
            for (int m = 0; m < 4; ++m)
                a[m] = *reinterpret_cast<const bfrag*>(
                    &Abuf[cur][((ki * 2 + hi) * 256 + wm * 128 + m * 32 + lo5) * 8]);
            #pragma unroll
            for (int m = 0; m < 4; ++m)
                acc[m] = __builtin_amdgcn_mfma_f32_32x32x16_bf16(
                    a[m], breg[cur][ki], acc[m], 0, 0, 0);
        }
        __builtin_amdgcn_s_barrier();          // reads done before overwrite
    }

    // Epilogue: bias + exact GELU + W2 dot; reduce over this wave's 128 f.
    const float* b1e = b1 + e * HFD;
    const float* W2e = W2 + e * HFD;
    const float kInvSqrt2 = 0.70710678118654752f;

    float po = 0.f;
    #pragma unroll
    for (int m = 0; m < 4; ++m) {
        const int base = mt * 256 + wm * 128 + m * 32 + 4 * hi;
        #pragma unroll
        for (int q = 0; q < 16; ++q) {
            const int frow = base + (q & 3) + 8 * (q >> 2);
            const float h = acc[m][q] + b1e[frow];
            po += 0.5f * h * (1.f + erff(h * kInvSqrt2)) * W2e[frow];
        }
    }
    po += __shfl_xor(po, 32, 64);

    if (hi == 0) o_part[wm][wn * 32 + lo5] = po;
    __syncthreads();

    if (tid < nt)
        atomicAdd(&P[cb + pos0 + tid], o_part[0][tid] + o_part[1][tid]);
}

// ---------------------------------------------------------------------------
// Combine: out[t] = w0 * P[gs0] + w1 * P[gs1].
// ---------------------------------------------------------------------------
__global__ __launch_bounds__(256)
void combine_kernel(const int* __restrict__ inv,
                    const float* __restrict__ P,
                    const float* __restrict__ wslot,
                    float* __restrict__ out_scores)
{
    const int t = blockIdx.x * 256 + threadIdx.x;
    if (t >= B_TOK) return;
    out_scores[t] = wslot[2 * t]     * P[inv[2 * t]]
                  + wslot[2 * t + 1] * P[inv[2 * t + 1]];
}

// ---------------------------------------------------------------------------
extern "C" void kernel_launch(void* const* d_in, const int* in_sizes, int n_in,
                              void* d_out, int out_size, void* d_ws, size_t ws_size,
                              hipStream_t stream)
{
    const float* x  = (const float*)d_in[0];
    const float* W1 = (const float*)d_in[1];
    const float* b1 = (const float*)d_in[2];
    const float* W2 = (const float*)d_in[3];
    const float* Wg = (const float*)d_in[4];
    const float* bg = (const float*)d_in[5];

    float* out        = (float*)d_out;
    float* out_scores = out;            // [B, 1]
    float* out_logits = out + B_TOK;    // [B, E]

    char* ws = (char*)d_ws;
    int*            counts = (int*)           (ws + OFF_COUNTS);
    int*            cbase  = (int*)           (ws + OFF_CBASE);
    int*            bucket = (int*)           (ws + OFF_BUCKET);
    float*          wslot  = (float*)         (ws + OFF_WSLOT);
    int*            route  = (int*)           (ws + OFF_ROUTE);
    int*            inv    = (int*)           (ws + OFF_INV);
    float*          P      = (float*)         (ws + OFF_P);
    float*          WgT    = (float*)         (ws + OFF_WGT);
    unsigned short* W1h    = (unsigned short*)(ws + OFF_W1H);
    unsigned short* xgT    = (unsigned short*)(ws + OFF_XGT);

    hipMemsetAsync(counts, 0, NE * sizeof(int), stream);
    hipMemsetAsync(P, 0, 33792 * sizeof(float), stream);

    wg_transpose_kernel<<<1, 256, 0, stream>>>(Wg, WgT);

    prep_w1_kernel<<<NE * NKSTEP, 256, 0, stream>>>(W1, W1h);

    gate_logits_kernel<<<B_TOK / 64, 256, 0, stream>>>(x, WgT, bg, out_logits,
                                                       wslot, route);

    route_kernel<<<B_TOK / 1024, 1024, 0, stream>>>(route, counts, bucket);

    prefix_kernel<<<1, 64, 0, stream>>>(counts, cbase);

    xgather_kernel<<<NE * (B_TOK / 64), 256, 0, stream>>>(
        x, bucket, counts, cbase, xgT, inv);

    expert_mfma_kernel<<<NE * 2 * PTMAX, 512, 0, stream>>>(
        xgT, W1h, b1, W2, counts, cbase, P);

    combine_kernel<<<B_TOK / 256, 256, 0, stream>>>(inv, P, wslot, out_scores);
}

// Round 9
// 327.256 us; speedup vs baseline: 1.2080x; 1.2080x over previous
//
#include <hip/hip_runtime.h>
#include <math.h>

// Problem constants (match reference)
#define B_TOK 16384
#define H_DIM 2048
#define NE    8
#define TOPK  2
#define HFD   512

#define BK 32
#define NKSTEP (H_DIM / BK)   // 64
#define PTMAX 129             // covers worst-case expert count

// Workspace layout (bytes)
static constexpr size_t OFF_COUNTS = 0;           // 32 B
static constexpr size_t OFF_CBASE  = 128;         // cbase[8] + cpad[8]
static constexpr size_t OFF_BUCKET = 1024;        // 512 KB
static constexpr size_t OFF_WSLOT  = 525312;      // 128 KB
static constexpr size_t OFF_ROUTE  = 656384;      // 64 KB
static constexpr size_t OFF_INV    = 721920;      // 128 KB
static constexpr size_t OFF_P      = 860160;      // 33792 floats
static constexpr size_t OFF_WGT    = 1u << 20;    // 8 replicas x 64 KB
static constexpr size_t OFF_W1H    = 2u << 20;    // 16 MB
static constexpr size_t OFF_XB     = 18874368;    // 64 MB bf16 x
// total ws use ~83 MB

typedef short bfrag __attribute__((ext_vector_type(8)));   // 8 bf16 (4 VGPR)
typedef float facc  __attribute__((ext_vector_type(16)));  // 32x32 accum

__device__ inline unsigned short f2bf(float f) {
    union { float f; unsigned u; } v; v.f = f;
    unsigned r = v.u + 0x7FFFu + ((v.u >> 16) & 1u);
    return (unsigned short)(r >> 16);
}
__device__ inline unsigned pack2(float lo, float hi) {
    return (unsigned)f2bf(lo) | ((unsigned)f2bf(hi) << 16);
}

__device__ __forceinline__ void gload_lds16(const void* g, void* l) {
    __builtin_amdgcn_global_load_lds(
        (const __attribute__((address_space(1))) unsigned int*)g,
        (__attribute__((address_space(3))) unsigned int*)l, 16, 0, 0);
}

// ---------------------------------------------------------------------------
// Transpose gate weights: Wg [H][E] -> 8 replicas of WgT [E][H].
// ---------------------------------------------------------------------------
__global__ __launch_bounds__(256)
void wg_transpose_kernel(const float* __restrict__ Wg,
                         float* __restrict__ WgT)
{
    const int t = threadIdx.x;
    #pragma unroll
    for (int rep = 0; rep < H_DIM / 256; ++rep) {
        const int h = rep * 256 + t;
        const float4 a = *reinterpret_cast<const float4*>(Wg + (size_t)h * NE);
        const float4 b = *reinterpret_cast<const float4*>(Wg + (size_t)h * NE + 4);
        #pragma unroll
        for (int rr = 0; rr < 8; ++rr) {
            float* W = WgT + (size_t)rr * (NE * H_DIM);
            W[0 * H_DIM + h] = a.x;  W[1 * H_DIM + h] = a.y;
            W[2 * H_DIM + h] = a.z;  W[3 * H_DIM + h] = a.w;
            W[4 * H_DIM + h] = b.x;  W[5 * H_DIM + h] = b.y;
            W[6 * H_DIM + h] = b.z;  W[7 * H_DIM + h] = b.w;
        }
    }
}

// ---------------------------------------------------------------------------
// Prep W1: [E][H][HF] fp32 -> per-(e, f-half) k-slot-major bf16 images:
//   W1h[(e*2+mt)*64 + kstep][slot(4)][f'(256)][j(8)]  (16 KB per image)
// ---------------------------------------------------------------------------
__global__ __launch_bounds__(256)
void prep_w1_kernel(const float* __restrict__ W1,
                    unsigned short* __restrict__ W1h)
{
    const int blk   = blockIdx.x;       // e*64 + kstep
    const int e     = blk >> 6;
    const int kstep = blk & 63;
    const int tid   = threadIdx.x;

    const float* src = W1 + ((size_t)e * H_DIM + kstep * BK) * HFD;

    #pragma unroll
    for (int s = 0; s < 4; ++s) {
        #pragma unroll
        for (int mt = 0; mt < 2; ++mt) {
            const int f = mt * 256 + tid;
            float v[8];
            #pragma unroll
            for (int j = 0; j < 8; ++j)
                v[j] = src[(size_t)(s * 8 + j) * HFD + f];   // coalesced
            uint4 p;
            p.x = pack2(v[0], v[1]); p.y = pack2(v[2], v[3]);
            p.z = pack2(v[4], v[5]); p.w = pack2(v[6], v[7]);
            *reinterpret_cast<uint4*>(
                W1h + ((size_t)((e * 2 + mt) * 64 + kstep)) * 8192
                    + (s * 256 + tid) * 8) = p;
        }
    }
}

// ---------------------------------------------------------------------------
// Gate logits: 256 blocks x 64 tokens; WgT staged once into LDS.
// Also converts x rows to bf16 (xb), which the expert kernel streams.
// ---------------------------------------------------------------------------
__global__ __launch_bounds__(256)
void gate_logits_kernel(const float* __restrict__ x,
                        const float* __restrict__ WgT,
                        const float* __restrict__ bg,
                        float* __restrict__ out_logits,
                        float* __restrict__ wslot,
                        int*   __restrict__ route,
                        unsigned short* __restrict__ xb)
{
    __shared__ float Wlds[NE * H_DIM];   // 64 KB

    const int tid = threadIdx.x;
    const float* Wsrc = WgT + (size_t)(blockIdx.x & 7) * (NE * H_DIM);
    #pragma unroll
    for (int i = 0; i < (NE * H_DIM) / (256 * 4); ++i) {
        const int idx = (i * 256 + tid) * 4;
        *reinterpret_cast<float4*>(&Wlds[idx]) =
            *reinterpret_cast<const float4*>(Wsrc + idx);
    }
    __syncthreads();

    const int w = tid >> 6, l = tid & 63;
    const int tbase = blockIdx.x * 64 + w * 16;

    for (int pass = 0; pass < 4; ++pass) {
        const int t0 = tbase + pass * 4;
        float acc[4][NE];
        #pragma unroll
        for (int j = 0; j < 4; ++j)
            #pragma unroll
            for (int e = 0; e < NE; ++e) acc[j][e] = 0.f;

        for (int i = 0; i < 8; ++i) {
            const int h = i * 256 + 4 * l;
            float4 xv[4];
            #pragma unroll
            for (int j = 0; j < 4; ++j)
                xv[j] = *reinterpret_cast<const float4*>(
                    x + (size_t)(t0 + j) * H_DIM + h);
            // bf16 conversion write (linear row layout == k-slot-major)
            #pragma unroll
            for (int j = 0; j < 4; ++j) {
                uint2 pk;
                pk.x = pack2(xv[j].x, xv[j].y);
                pk.y = pack2(xv[j].z, xv[j].w);
                *reinterpret_cast<uint2*>(xb + (size_t)(t0 + j) * H_DIM + h) = pk;
            }
            #pragma unroll
            for (int e = 0; e < NE; ++e) {
                const float4 wv = *reinterpret_cast<const float4*>(&Wlds[e * H_DIM + h]);
                #pragma unroll
                for (int j = 0; j < 4; ++j)
                    acc[j][e] += xv[j].x * wv.x + xv[j].y * wv.y
                               + xv[j].z * wv.z + xv[j].w * wv.w;
            }
        }

        #pragma unroll
        for (int j = 0; j < 4; ++j)
            #pragma unroll
            for (int e = 0; e < NE; ++e)
                #pragma unroll
                for (int off = 32; off > 0; off >>= 1)
                    acc[j][e] += __shfl_xor(acc[j][e], off, 64);

        if (l == 0) {
            #pragma unroll
            for (int j = 0; j < 4; ++j) {
                const int tok = t0 + j;
                float lg[NE];
                #pragma unroll
                for (int e = 0; e < NE; ++e) lg[e] = acc[j][e] + bg[e];

                float4* lo = reinterpret_cast<float4*>(out_logits + (size_t)tok * NE);
                lo[0] = make_float4(lg[0], lg[1], lg[2], lg[3]);
                lo[1] = make_float4(lg[4], lg[5], lg[6], lg[7]);

                int i0 = 0; float v0 = lg[0];
                #pragma unroll
                for (int e = 1; e < NE; ++e)
                    if (lg[e] > v0) { v0 = lg[e]; i0 = e; }
                int i1 = -1; float v1 = -3.4e38f;
                #pragma unroll
                for (int e = 0; e < NE; ++e)
                    if (e != i0 && lg[e] > v1) { v1 = lg[e]; i1 = e; }

                const float w0 = 1.f / (1.f + expf(v1 - v0));
                wslot[tok * 2]     = w0;
                wslot[tok * 2 + 1] = 1.f - w0;
                route[tok] = i0 | (i1 << 8);
            }
        }
    }
}

// ---------------------------------------------------------------------------
// Route/bucket: LDS-aggregated histogram; 8 global atomics per block.
// ---------------------------------------------------------------------------
__global__ __launch_bounds__(1024)
void route_kernel(const int* __restrict__ route,
                  int* __restrict__ counts,
                  int* __restrict__ bucket)
{
    __shared__ int lcnt[NE];
    __shared__ int lbase[NE];
    const int tid = threadIdx.x;
    const int tok = blockIdx.x * 1024 + tid;

    if (tid < NE) lcnt[tid] = 0;
    __syncthreads();

    const int rt = route[tok];
    const int i0 = rt & 255;
    const int i1 = rt >> 8;
    const int r0 = atomicAdd(&lcnt[i0], 1);
    const int r1 = atomicAdd(&lcnt[i1], 1);
    __syncthreads();

    if (tid < NE) lbase[tid] = atomicAdd(&counts[tid], lcnt[tid]);
    __syncthreads();

    bucket[i0 * B_TOK + lbase[i0] + r0] = tok * 2;
    bucket[i1 * B_TOK + lbase[i1] + r1] = tok * 2 + 1;
}

// ---------------------------------------------------------------------------
// Prefix: cbase[e] = row base; cpad[e] = count padded to 128.
// ---------------------------------------------------------------------------
__global__ void prefix_kernel(const int* __restrict__ counts,
                              int* __restrict__ cbase)
{
    if (threadIdx.x == 0 && blockIdx.x == 0) {
        int acc = 0;
        for (int e = 0; e < NE; ++e) {
            const int cp = ((counts[e] + 127) >> 7) << 7;
            cbase[e]      = acc;
            cbase[NE + e] = cp;
            acc += cp;
        }
    }
}

// ---------------------------------------------------------------------------
// invfill: inv[entry] = global P row for each bucket slot.
// ---------------------------------------------------------------------------
__global__ __launch_bounds__(256)
void invfill_kernel(const int* __restrict__ bucket,
                    const int* __restrict__ counts,
                    const int* __restrict__ cbase,
                    int* __restrict__ inv)
{
    const int e   = blockIdx.x & 7;
    const int pos = (blockIdx.x >> 3) * 256 + threadIdx.x;
    if (pos < counts[e]) inv[bucket[e * B_TOK + pos]] = cbase[e] + pos;
}

// ---------------------------------------------------------------------------
// Expert MFMA: block = (e, f-half mt, 128-pos tile). 512 thr / 8 waves
// (wm = w&1: 128 f rows; wn = w>>1: 32 pos cols). acc 4x f32x16.
// A: depth-4 LDS pipeline (4 x 16 KB) via linear global_load_lds.
// B: depth-4 VGPR pipeline; each lane streams ITS OWN token row from xb
//    (consecutive 64 B per step, imm-offset folded) -- no LDS, no barrier.
// Counted vmcnt(12) = 3 steps of latency cover; raw double barriers/step;
// K-loop fully unrolled (all buffer indices static). 65 KB LDS + <=128
// VGPR (launch_bounds 512,4) -> 2 blocks/CU co-resident.
// ---------------------------------------------------------------------------
__global__ __launch_bounds__(512, 4)
void expert_mfma_kernel(const unsigned short* __restrict__ xb,
                        const unsigned short* __restrict__ W1h,
                        const float* __restrict__ b1,
                        const float* __restrict__ W2,
                        const int* __restrict__ counts,
                        const int* __restrict__ cbase,
                        const int* __restrict__ bucket,
                        float* __restrict__ P)
{
    const int e  = blockIdx.x & 7;
    const int r  = blockIdx.x >> 3;
    const int mt = r & 1;
    const int pt = r >> 1;
    const int n  = counts[e];
    const int pos0 = pt * 128;
    if (pos0 >= n) return;
    const int nt = min(128, n - pos0);
    const int cb = cbase[e];

    __shared__ unsigned short Abuf[4][8192];   // 4 x 16 KB [slot4][f'256][8]
    __shared__ float o_part[2][128];

    const int tid = threadIdx.x;
    const int w   = tid >> 6;
    const int l   = tid & 63;
    const int lo5 = l & 31;
    const int hi  = l >> 5;
    const int wm  = w & 1;       // f-group (128 rows)
    const int wn  = w >> 1;      // pos-group (32 cols)

    const unsigned short* Asrc = W1h + (size_t)((e * 2 + mt) * 64) * 8192;
    const int aoff = w * 1024 + l * 8;   // shorts; = wave-base + lane*16B

    // Per-lane token row stream (B operand).
    const int posl = pos0 + wn * 32 + lo5;
    const int tok  = bucket[e * B_TOK + min(posl, n - 1)] >> 1;
    const unsigned short* myrow = xb + (size_t)tok * H_DIM;

    facc acc[4];
    #pragma unroll
    for (int m = 0; m < 4; ++m)
        #pragma unroll
        for (int q = 0; q < 16; ++q) acc[m][q] = 0.f;

    bfrag breg[4][2];

    // 2 gload_lds (A) + 2 VGPR loads (B) = exactly 4 vmcnt items per step.
    #define STAGE(KK) do {                                                     \
        const unsigned short* as_ = Asrc + (size_t)(KK) * 8192;                \
        gload_lds16(as_ + aoff,       &Abuf[(KK) & 3][aoff]);                  \
        gload_lds16(as_ + aoff + 512, &Abuf[(KK) & 3][aoff + 512]);            \
        breg[(KK) & 3][0] = *reinterpret_cast<const bfrag*>(                   \
            myrow + (KK) * 32 + hi * 8);                                       \
        breg[(KK) & 3][1] = *reinterpret_cast<const bfrag*>(                   \
            myrow + (KK) * 32 + hi * 8 + 16);                                  \
    } while (0)

    STAGE(0); STAGE(1); STAGE(2);        // 12 items in flight

    #pragma unroll
    for (int kk = 0; kk < NKSTEP; ++kk) {
        if (kk < NKSTEP - 3) {
            STAGE(kk + 3);
            asm volatile("s_waitcnt vmcnt(12)" ::: "memory");  // step kk landed
        } else if (kk == NKSTEP - 3) {
            asm volatile("s_waitcnt vmcnt(8)" ::: "memory");
        } else if (kk == NKSTEP - 2) {
            asm volatile("s_waitcnt vmcnt(4)" ::: "memory");
        } else {
            asm volatile("s_waitcnt vmcnt(0)" ::: "memory");
        }
        __builtin_amdgcn_s_barrier();        // everyone's step-kk A landed

        #pragma unroll
        for (int ki = 0; ki < 2; ++ki) {
            bfrag a[4];
            #pragma unroll
            for (int m = 0; m < 4; ++m)
                a[m] = *reinterpret_cast<const bfrag*>(
                    &Abuf[kk & 3][((ki * 2 + hi) * 256 + wm * 128 + m * 32 + lo5) * 8]);
            #pragma unroll
            for (int m = 0; m < 4; ++m)
                acc[m] = __builtin_amdgcn_mfma_f32_32x32x16_bf16(
                    a[m], breg[kk & 3][ki], acc[m], 0, 0, 0);
        }
        __builtin_amdgcn_s_barrier();        // reads done before buf reuse
    }
    #undef STAGE

    // Epilogue: bias + exact GELU + W2 dot; reduce over this wave's 128 f.
    const float* b1e = b1 + e * HFD;
    const float* W2e = W2 + e * HFD;
    const float kInvSqrt2 = 0.70710678118654752f;

    float po = 0.f;
    #pragma unroll
    for (int m = 0; m < 4; ++m) {
        const int base = mt * 256 + wm * 128 + m * 32 + 4 * hi;
        #pragma unroll
        for (int q = 0; q < 16; ++q) {
            const int frow = base + (q & 3) + 8 * (q >> 2);
            const float h = acc[m][q] + b1e[frow];
            po += 0.5f * h * (1.f + erff(h * kInvSqrt2)) * W2e[frow];
        }
    }
    po += __shfl_xor(po, 32, 64);

    if (hi == 0) o_part[wm][wn * 32 + lo5] = po;
    __syncthreads();

    if (tid < nt)
        atomicAdd(&P[cb + pos0 + tid], o_part[0][tid] + o_part[1][tid]);
}

// ---------------------------------------------------------------------------
// Combine: out[t] = w0 * P[gs0] + w1 * P[gs1].  Deterministic.
// ---------------------------------------------------------------------------
__global__ __launch_bounds__(256)
void combine_kernel(const int* __restrict__ inv,
                    const float* __restrict__ P,
                    const float* __restrict__ wslot,
                    float* __restrict__ out_scores)
{
    const int t = blockIdx.x * 256 + threadIdx.x;
    if (t >= B_TOK) return;
    out_scores[t] = wslot[2 * t]     * P[inv[2 * t]]
                  + wslot[2 * t + 1] * P[inv[2 * t + 1]];
}

// ---------------------------------------------------------------------------
extern "C" void kernel_launch(void* const* d_in, const int* in_sizes, int n_in,
                              void* d_out, int out_size, void* d_ws, size_t ws_size,
                              hipStream_t stream)
{
    const float* x  = (const float*)d_in[0];
    const float* W1 = (const float*)d_in[1];
    const float* b1 = (const float*)d_in[2];
    const float* W2 = (const float*)d_in[3];
    const float* Wg = (const float*)d_in[4];
    const float* bg = (const float*)d_in[5];

    float* out        = (float*)d_out;
    float* out_scores = out;            // [B, 1]
    float* out_logits = out + B_TOK;    // [B, E]

    char* ws = (char*)d_ws;
    int*            counts = (int*)           (ws + OFF_COUNTS);
    int*            cbase  = (int*)           (ws + OFF_CBASE);
    int*            bucket = (int*)           (ws + OFF_BUCKET);
    float*          wslot  = (float*)         (ws + OFF_WSLOT);
    int*            route  = (int*)           (ws + OFF_ROUTE);
    int*            inv    = (int*)           (ws + OFF_INV);
    float*          P      = (float*)         (ws + OFF_P);
    float*          WgT    = (float*)         (ws + OFF_WGT);
    unsigned short* W1h    = (unsigned short*)(ws + OFF_W1H);
    unsigned short* xb     = (unsigned short*)(ws + OFF_XB);

    hipMemsetAsync(counts, 0, NE * sizeof(int), stream);
    hipMemsetAsync(P, 0, 33792 * sizeof(float), stream);

    wg_transpose_kernel<<<1, 256, 0, stream>>>(Wg, WgT);

    prep_w1_kernel<<<NE * NKSTEP, 256, 0, stream>>>(W1, W1h);

    gate_logits_kernel<<<B_TOK / 64, 256, 0, stream>>>(x, WgT, bg, out_logits,
                                                       wslot, route, xb);

    route_kernel<<<B_TOK / 1024, 1024, 0, stream>>>(route, counts, bucket);

    prefix_kernel<<<1, 64, 0, stream>>>(counts, cbase);

    invfill_kernel<<<NE * (B_TOK / 256), 256, 0, stream>>>(bucket, counts,
                                                           cbase, inv);

    expert_mfma_kernel<<<NE * 2 * PTMAX, 512, 0, stream>>>(
        xb, W1h, b1, W2, counts, cbase, bucket, P);

    combine_kernel<<<B_TOK / 256, 256, 0, stream>>>(inv, P, wslot, out_scores);
}

// Round 10
// 299.857 us; speedup vs baseline: 1.3184x; 1.0914x over previous
//
#include <hip/hip_runtime.h>
#include <math.h>

// Problem constants (match reference)
#define B_TOK 16384
#define H_DIM 2048
#define NE    8
#define TOPK  2
#define HFD   512

#define BK 32
#define NKSTEP (H_DIM / BK)   // 64
#define PTMAX 129             // covers worst-case expert count

// Workspace layout (bytes)
static constexpr size_t OFF_COUNTS = 0;           // 32 B
static constexpr size_t OFF_CBASE  = 128;         // cbase[8] + cpad[8]
static constexpr size_t OFF_BUCKET = 1024;        // 512 KB
static constexpr size_t OFF_WSLOT  = 525312;      // 128 KB
static constexpr size_t OFF_ROUTE  = 656384;      // 64 KB
static constexpr size_t OFF_INV    = 721920;      // 128 KB
static constexpr size_t OFF_P      = 860160;      // 33792 floats
static constexpr size_t OFF_WGT    = 1u << 20;    // 8 replicas x 64 KB
static constexpr size_t OFF_W1H    = 2u << 20;    // 16 MB
static constexpr size_t OFF_XB     = 18874368;    // 64 MB bf16 x
// total ws use ~83 MB

typedef short bfrag __attribute__((ext_vector_type(8)));   // 8 bf16 (4 VGPR)
typedef float facc  __attribute__((ext_vector_type(16)));  // 32x32 accum

__device__ inline unsigned short f2bf(float f) {
    union { float f; unsigned u; } v; v.f = f;
    unsigned r = v.u + 0x7FFFu + ((v.u >> 16) & 1u);
    return (unsigned short)(r >> 16);
}
__device__ inline unsigned pack2(float lo, float hi) {
    return (unsigned)f2bf(lo) | ((unsigned)f2bf(hi) << 16);
}

__device__ __forceinline__ void gload_lds16(const void* g, void* l) {
    __builtin_amdgcn_global_load_lds(
        (const __attribute__((address_space(1))) unsigned int*)g,
        (__attribute__((address_space(3))) unsigned int*)l, 16, 0, 0);
}

// ---------------------------------------------------------------------------
// Transpose gate weights: Wg [H][E] -> 8 replicas of WgT [E][H].
// ---------------------------------------------------------------------------
__global__ __launch_bounds__(256)
void wg_transpose_kernel(const float* __restrict__ Wg,
                         float* __restrict__ WgT)
{
    const int t = threadIdx.x;
    #pragma unroll
    for (int rep = 0; rep < H_DIM / 256; ++rep) {
        const int h = rep * 256 + t;
        const float4 a = *reinterpret_cast<const float4*>(Wg + (size_t)h * NE);
        const float4 b = *reinterpret_cast<const float4*>(Wg + (size_t)h * NE + 4);
        #pragma unroll
        for (int rr = 0; rr < 8; ++rr) {
            float* W = WgT + (size_t)rr * (NE * H_DIM);
            W[0 * H_DIM + h] = a.x;  W[1 * H_DIM + h] = a.y;
            W[2 * H_DIM + h] = a.z;  W[3 * H_DIM + h] = a.w;
            W[4 * H_DIM + h] = b.x;  W[5 * H_DIM + h] = b.y;
            W[6 * H_DIM + h] = b.z;  W[7 * H_DIM + h] = b.w;
        }
    }
}

// ---------------------------------------------------------------------------
// Prep W1: [E][H][HF] fp32 -> per-(e, f-half) k-slot-major bf16 images:
//   W1h[(e*2+mt)*64 + kstep][slot(4)][f'(256)][j(8)]  (16 KB per image)
// ---------------------------------------------------------------------------
__global__ __launch_bounds__(256)
void prep_w1_kernel(const float* __restrict__ W1,
                    unsigned short* __restrict__ W1h)
{
    const int blk   = blockIdx.x;       // e*64 + kstep
    const int e     = blk >> 6;
    const int kstep = blk & 63;
    const int tid   = threadIdx.x;

    const float* src = W1 + ((size_t)e * H_DIM + kstep * BK) * HFD;

    #pragma unroll
    for (int s = 0; s < 4; ++s) {
        #pragma unroll
        for (int mt = 0; mt < 2; ++mt) {
            const int f = mt * 256 + tid;
            float v[8];
            #pragma unroll
            for (int j = 0; j < 8; ++j)
                v[j] = src[(size_t)(s * 8 + j) * HFD + f];   // coalesced
            uint4 p;
            p.x = pack2(v[0], v[1]); p.y = pack2(v[2], v[3]);
            p.z = pack2(v[4], v[5]); p.w = pack2(v[6], v[7]);
            *reinterpret_cast<uint4*>(
                W1h + ((size_t)((e * 2 + mt) * 64 + kstep)) * 8192
                    + (s * 256 + tid) * 8) = p;
        }
    }
}

// ---------------------------------------------------------------------------
// Gate logits: 256 blocks x 64 tokens; WgT staged once into LDS.
// Also converts x rows to bf16 (xb), which the expert kernel gathers.
// ---------------------------------------------------------------------------
__global__ __launch_bounds__(256)
void gate_logits_kernel(const float* __restrict__ x,
                        const float* __restrict__ WgT,
                        const float* __restrict__ bg,
                        float* __restrict__ out_logits,
                        float* __restrict__ wslot,
                        int*   __restrict__ route,
                        unsigned short* __restrict__ xb)
{
    __shared__ float Wlds[NE * H_DIM];   // 64 KB

    const int tid = threadIdx.x;
    const float* Wsrc = WgT + (size_t)(blockIdx.x & 7) * (NE * H_DIM);
    #pragma unroll
    for (int i = 0; i < (NE * H_DIM) / (256 * 4); ++i) {
        const int idx = (i * 256 + tid) * 4;
        *reinterpret_cast<float4*>(&Wlds[idx]) =
            *reinterpret_cast<const float4*>(Wsrc + idx);
    }
    __syncthreads();

    const int w = tid >> 6, l = tid & 63;
    const int tbase = blockIdx.x * 64 + w * 16;

    for (int pass = 0; pass < 4; ++pass) {
        const int t0 = tbase + pass * 4;
        float acc[4][NE];
        #pragma unroll
        for (int j = 0; j < 4; ++j)
            #pragma unroll
            for (int e = 0; e < NE; ++e) acc[j][e] = 0.f;

        for (int i = 0; i < 8; ++i) {
            const int h = i * 256 + 4 * l;
            float4 xv[4];
            #pragma unroll
            for (int j = 0; j < 4; ++j)
                xv[j] = *reinterpret_cast<const float4*>(
                    x + (size_t)(t0 + j) * H_DIM + h);
            #pragma unroll
            for (int j = 0; j < 4; ++j) {
                uint2 pk;
                pk.x = pack2(xv[j].x, xv[j].y);
                pk.y = pack2(xv[j].z, xv[j].w);
                *reinterpret_cast<uint2*>(xb + (size_t)(t0 + j) * H_DIM + h) = pk;
            }
            #pragma unroll
            for (int e = 0; e < NE; ++e) {
                const float4 wv = *reinterpret_cast<const float4*>(&Wlds[e * H_DIM + h]);
                #pragma unroll
                for (int j = 0; j < 4; ++j)
                    acc[j][e] += xv[j].x * wv.x + xv[j].y * wv.y
                               + xv[j].z * wv.z + xv[j].w * wv.w;
            }
        }

        #pragma unroll
        for (int j = 0; j < 4; ++j)
            #pragma unroll
            for (int e = 0; e < NE; ++e)
                #pragma unroll
                for (int off = 32; off > 0; off >>= 1)
                    acc[j][e] += __shfl_xor(acc[j][e], off, 64);

        if (l == 0) {
            #pragma unroll
            for (int j = 0; j < 4; ++j) {
                const int tok = t0 + j;
                float lg[NE];
                #pragma unroll
                for (int e = 0; e < NE; ++e) lg[e] = acc[j][e] + bg[e];

                float4* lo = reinterpret_cast<float4*>(out_logits + (size_t)tok * NE);
                lo[0] = make_float4(lg[0], lg[1], lg[2], lg[3]);
                lo[1] = make_float4(lg[4], lg[5], lg[6], lg[7]);

                int i0 = 0; float v0 = lg[0];
                #pragma unroll
                for (int e = 1; e < NE; ++e)
                    if (lg[e] > v0) { v0 = lg[e]; i0 = e; }
                int i1 = -1; float v1 = -3.4e38f;
                #pragma unroll
                for (int e = 0; e < NE; ++e)
                    if (e != i0 && lg[e] > v1) { v1 = lg[e]; i1 = e; }

                const float w0 = 1.f / (1.f + expf(v1 - v0));
                wslot[tok * 2]     = w0;
                wslot[tok * 2 + 1] = 1.f - w0;
                route[tok] = i0 | (i1 << 8);
            }
        }
    }
}

// ---------------------------------------------------------------------------
// Route/bucket: LDS-aggregated histogram; 8 global atomics per block.
// ---------------------------------------------------------------------------
__global__ __launch_bounds__(1024)
void route_kernel(const int* __restrict__ route,
                  int* __restrict__ counts,
                  int* __restrict__ bucket)
{
    __shared__ int lcnt[NE];
    __shared__ int lbase[NE];
    const int tid = threadIdx.x;
    const int tok = blockIdx.x * 1024 + tid;

    if (tid < NE) lcnt[tid] = 0;
    __syncthreads();

    const int rt = route[tok];
    const int i0 = rt & 255;
    const int i1 = rt >> 8;
    const int r0 = atomicAdd(&lcnt[i0], 1);
    const int r1 = atomicAdd(&lcnt[i1], 1);
    __syncthreads();

    if (tid < NE) lbase[tid] = atomicAdd(&counts[tid], lcnt[tid]);
    __syncthreads();

    bucket[i0 * B_TOK + lbase[i0] + r0] = tok * 2;
    bucket[i1 * B_TOK + lbase[i1] + r1] = tok * 2 + 1;
}

// ---------------------------------------------------------------------------
// Prefix: cbase[e] = row base; cpad[e] = count padded to 128.
// ---------------------------------------------------------------------------
__global__ void prefix_kernel(const int* __restrict__ counts,
                              int* __restrict__ cbase)
{
    if (threadIdx.x == 0 && blockIdx.x == 0) {
        int acc = 0;
        for (int e = 0; e < NE; ++e) {
            const int cp = ((counts[e] + 127) >> 7) << 7;
            cbase[e]      = acc;
            cbase[NE + e] = cp;
            acc += cp;
        }
    }
}

// ---------------------------------------------------------------------------
// invfill: inv[entry] = global P row for each bucket slot.
// ---------------------------------------------------------------------------
__global__ __launch_bounds__(256)
void invfill_kernel(const int* __restrict__ bucket,
                    const int* __restrict__ counts,
                    const int* __restrict__ cbase,
                    int* __restrict__ inv)
{
    const int e   = blockIdx.x & 7;
    const int pos = (blockIdx.x >> 3) * 256 + threadIdx.x;
    if (pos < counts[e]) inv[bucket[e * B_TOK + pos]] = cbase[e] + pos;
}

// ---------------------------------------------------------------------------
// Expert MFMA: block = (e, f-half mt, 128-pos tile). 512 thr / 8 waves
// (wm = w&1: 128 f rows; wn = w>>1: 32 pos cols). acc 4x f32x16.
// A: depth-3 LDS pipeline (3 x 16 KB) via linear global_load_lds.
// X: FULL-LINE gather -- 4 consecutive lanes cover one token row's 64 B
//    K-chunk (16 lines/instr, each line requested exactly once), landed in
//    VGPR, then issue-early/write-late ds_write into a pad-40-short LDS
//    tile (80 B row stride => rotated banks, ~conflict-free b128 reads).
// Single barrier/step; end-of-step vmcnt(2) gives A ~1.5-step slack and
// hides the X load under the MFMA cluster (T14). 79 KB LDS -> 2 blocks/CU.
// ---------------------------------------------------------------------------
__global__ __launch_bounds__(512, 2)
void expert_mfma_kernel(const unsigned short* __restrict__ xb,
                        const unsigned short* __restrict__ W1h,
                        const float* __restrict__ b1,
                        const float* __restrict__ W2,
                        const int* __restrict__ counts,
                        const int* __restrict__ cbase,
                        const int* __restrict__ bucket,
                        float* __restrict__ P)
{
    const int e  = blockIdx.x & 7;
    const int r  = blockIdx.x >> 3;
    const int mt = r & 1;
    const int pt = r >> 1;
    const int n  = counts[e];
    const int pos0 = pt * 128;
    if (pos0 >= n) return;
    const int nt = min(128, n - pos0);
    const int cb = cbase[e];

    __shared__ unsigned short Abuf[3][8192];     // 3 x 16 KB [slot4][f'256][8]
    __shared__ unsigned short Xbuf[3][128 * 40]; // 3 x 10 KB, pad-40 rows
    __shared__ float o_part[2][128];

    const int tid = threadIdx.x;
    const int w   = tid >> 6;
    const int l   = tid & 63;
    const int lo5 = l & 31;
    const int hi  = l >> 5;
    const int wm  = w & 1;       // f-group (128 rows)
    const int wn  = w >> 1;      // pos-group (32 cols)

    const unsigned short* Asrc = W1h + (size_t)((e * 2 + mt) * 64) * 8192;
    const int aoff = w * 1024 + l * 8;   // shorts

    // X gather role: thread t covers 16 B of row (t>>2), sub-chunk (t&3).
    const int gp  = tid >> 2;            // pos 0..127
    const int sub = tid & 3;
    const int gtok = bucket[e * B_TOK + min(pos0 + gp, n - 1)] >> 1;
    const unsigned short* myx = xb + (size_t)gtok * H_DIM + sub * 8;
    const int xoff = gp * 40 + sub * 8;  // LDS shorts offset (pad-40 stride)

    facc acc[4];
    #pragma unroll
    for (int m = 0; m < 4; ++m)
        #pragma unroll
        for (int q = 0; q < 16; ++q) acc[m][q] = 0.f;

    uint4 xr;

    #define ISSUE_A(KK, S) do {                                                \
        const unsigned short* as_ = Asrc + (size_t)(KK) * 8192;                \
        gload_lds16(as_ + aoff,       &Abuf[S][aoff]);                         \
        gload_lds16(as_ + aoff + 512, &Abuf[S][aoff + 512]);                   \
    } while (0)

    // prologue: steps 0 and 1 fully staged
    xr = *reinterpret_cast<const uint4*>(myx + 0 * 32);
    ISSUE_A(0, 0);
    asm volatile("s_waitcnt vmcnt(2)" ::: "memory");     // xr(step0) landed
    *reinterpret_cast<uint4*>(&Xbuf[0][xoff]) = xr;
    xr = *reinterpret_cast<const uint4*>(myx + 1 * 32);
    ISSUE_A(1, 1);
    asm volatile("s_waitcnt vmcnt(2)" ::: "memory");     // xr(step1) landed
    *reinterpret_cast<uint4*>(&Xbuf[1][xoff]) = xr;
    asm volatile("s_waitcnt lgkmcnt(0)" ::: "memory");
    __builtin_amdgcn_s_barrier();                        // step 0/1 X visible

    for (int kk = 0; kk < NKSTEP; ++kk) {
        const int cur = kk % 3;
        const int nxt = (kk + 2) % 3;

        if (kk + 2 < NKSTEP) {
            xr = *reinterpret_cast<const uint4*>(myx + (kk + 2) * 32);
            ISSUE_A(kk + 2, nxt);
        }
        if (kk == NKSTEP - 1)
            asm volatile("s_waitcnt vmcnt(0)" ::: "memory");

        // compute step kk
        #pragma unroll
        for (int ks = 0; ks < 2; ++ks) {
            const int slot = ks * 2 + hi;
            bfrag a[4];
            #pragma unroll
            for (int m = 0; m < 4; ++m)
                a[m] = *reinterpret_cast<const bfrag*>(
                    &Abuf[cur][(slot * 256 + wm * 128 + m * 32 + lo5) * 8]);
            const bfrag bb = *reinterpret_cast<const bfrag*>(
                &Xbuf[cur][(wn * 32 + lo5) * 40 + slot * 8]);
            #pragma unroll
            for (int m = 0; m < 4; ++m)
                acc[m] = __builtin_amdgcn_mfma_f32_32x32x16_bf16(
                    a[m], bb, acc[m], 0, 0, 0);
        }

        if (kk + 2 < NKSTEP) {
            // xr landed by now (hidden under MFMA); A of step kk+1 forced too.
            asm volatile("s_waitcnt vmcnt(2)" ::: "memory");
            *reinterpret_cast<uint4*>(&Xbuf[nxt][xoff]) = xr;
        }
        asm volatile("s_waitcnt lgkmcnt(0)" ::: "memory");
        __builtin_amdgcn_s_barrier();
    }
    #undef ISSUE_A

    // Epilogue: bias + exact GELU + W2 dot; reduce over this wave's 128 f.
    const float* b1e = b1 + e * HFD;
    const float* W2e = W2 + e * HFD;
    const float kInvSqrt2 = 0.70710678118654752f;

    float po = 0.f;
    #pragma unroll
    for (int m = 0; m < 4; ++m) {
        const int base = mt * 256 + wm * 128 + m * 32 + 4 * hi;
        #pragma unroll
        for (int q = 0; q < 16; ++q) {
            const int frow = base + (q & 3) + 8 * (q >> 2);
            const float h = acc[m][q] + b1e[frow];
            po += 0.5f * h * (1.f + erff(h * kInvSqrt2)) * W2e[frow];
        }
    }
    po += __shfl_xor(po, 32, 64);

    if (hi == 0) o_part[wm][wn * 32 + lo5] = po;
    __syncthreads();

    if (tid < nt)
        atomicAdd(&P[cb + pos0 + tid], o_part[0][tid] + o_part[1][tid]);
}

// ---------------------------------------------------------------------------
// Combine: out[t] = w0 * P[gs0] + w1 * P[gs1].  Deterministic.
// ---------------------------------------------------------------------------
__global__ __launch_bounds__(256)
void combine_kernel(const int* __restrict__ inv,
                    const float* __restrict__ P,
                    const float* __restrict__ wslot,
                    float* __restrict__ out_scores)
{
    const int t = blockIdx.x * 256 + threadIdx.x;
    if (t >= B_TOK) return;
    out_scores[t] = wslot[2 * t]     * P[inv[2 * t]]
                  + wslot[2 * t + 1] * P[inv[2 * t + 1]];
}

// ---------------------------------------------------------------------------
extern "C" void kernel_launch(void* const* d_in, const int* in_sizes, int n_in,
                              void* d_out, int out_size, void* d_ws, size_t ws_size,
                              hipStream_t stream)
{
    const float* x  = (const float*)d_in[0];
    const float* W1 = (const float*)d_in[1];
    const float* b1 = (const float*)d_in[2];
    const float* W2 = (const float*)d_in[3];
    const float* Wg = (const float*)d_in[4];
    const float* bg = (const float*)d_in[5];

    float* out        = (float*)d_out;
    float* out_scores = out;            // [B, 1]
    float* out_logits = out + B_TOK;    // [B, E]

    char* ws = (char*)d_ws;
    int*            counts = (int*)           (ws + OFF_COUNTS);
    int*            cbase  = (int*)           (ws + OFF_CBASE);
    int*            bucket = (int*)           (ws + OFF_BUCKET);
    float*          wslot  = (float*)         (ws + OFF_WSLOT);
    int*            route  = (int*)           (ws + OFF_ROUTE);
    int*            inv    = (int*)           (ws + OFF_INV);
    float*          P      = (float*)         (ws + OFF_P);
    float*          WgT    = (float*)         (ws + OFF_WGT);
    unsigned short* W1h    = (unsigned short*)(ws + OFF_W1H);
    unsigned short* xb     = (unsigned short*)(ws + OFF_XB);

    hipMemsetAsync(counts, 0, NE * sizeof(int), stream);
    hipMemsetAsync(P, 0, 33792 * sizeof(float), stream);

    wg_transpose_kernel<<<1, 256, 0, stream>>>(Wg, WgT);

    prep_w1_kernel<<<NE * NKSTEP, 256, 0, stream>>>(W1, W1h);

    gate_logits_kernel<<<B_TOK / 64, 256, 0, stream>>>(x, WgT, bg, out_logits,
                                                       wslot, route, xb);

    route_kernel<<<B_TOK / 1024, 1024, 0, stream>>>(route, counts, bucket);

    prefix_kernel<<<1, 64, 0, stream>>>(counts, cbase);

    invfill_kernel<<<NE * (B_TOK / 256), 256, 0, stream>>>(bucket, counts,
                                                           cbase, inv);

    expert_mfma_kernel<<<NE * 2 * PTMAX, 512, 0, stream>>>(
        xb, W1h, b1, W2, counts, cbase, bucket, P);

    combine_kernel<<<B_TOK / 256, 256, 0, stream>>>(inv, P, wslot, out_scores);
}

// Round 11
// 246.648 us; speedup vs baseline: 1.6028x; 1.2157x over previous
//
#include <hip/hip_runtime.h>
#include <math.h>

// Problem constants (match reference)
#define B_TOK 16384
#define H_DIM 2048
#define NE    8
#define TOPK  2
#define HFD   512

#define BK 64
#define NKSTEP (H_DIM / BK)   // 32
#define PTMAX 129             // covers worst-case expert count
#define PROWS 33792           // padded P rows total (8 experts, 128-padded)

// Workspace layout (bytes)
static constexpr size_t OFF_COUNTS = 0;           // 32 B
static constexpr size_t OFF_CBASE  = 128;         // cbase[8] + cpad[8]
static constexpr size_t OFF_BUCKET = 1024;        // 512 KB
static constexpr size_t OFF_WSLOT  = 525312;      // 128 KB
static constexpr size_t OFF_ROUTE  = 656384;      // 64 KB
static constexpr size_t OFF_INV    = 721920;      // 128 KB -> 849920
static constexpr size_t OFF_WGT    = 1u << 20;    // 8 replicas x 64 KB = 512 KB
static constexpr size_t OFF_P4     = 1572864;     // 4 x 33792 floats = 528 KB
static constexpr size_t OFF_W1Q    = 4u << 20;    // 16 MB -> ends 20 MB
static constexpr size_t OFF_XB     = 20971520;    // 64 MB bf16 x -> ends 84 MB

typedef short bfrag __attribute__((ext_vector_type(8)));   // 8 bf16 (4 VGPR)
typedef float facc  __attribute__((ext_vector_type(16)));  // 32x32 accum

__device__ inline unsigned short f2bf(float f) {
    union { float f; unsigned u; } v; v.f = f;
    unsigned r = v.u + 0x7FFFu + ((v.u >> 16) & 1u);
    return (unsigned short)(r >> 16);
}
__device__ inline unsigned pack2(float lo, float hi) {
    return (unsigned)f2bf(lo) | ((unsigned)f2bf(hi) << 16);
}

__device__ __forceinline__ void gload_lds16(const void* g, void* l) {
    __builtin_amdgcn_global_load_lds(
        (const __attribute__((address_space(1))) unsigned int*)g,
        (__attribute__((address_space(3))) unsigned int*)l, 16, 0, 0);
}

// ---------------------------------------------------------------------------
// Transpose gate weights: Wg [H][E] -> 8 replicas of WgT [E][H].
// ---------------------------------------------------------------------------
__global__ __launch_bounds__(256)
void wg_transpose_kernel(const float* __restrict__ Wg,
                         float* __restrict__ WgT)
{
    const int t = threadIdx.x;
    #pragma unroll
    for (int rep = 0; rep < H_DIM / 256; ++rep) {
        const int h = rep * 256 + t;
        const float4 a = *reinterpret_cast<const float4*>(Wg + (size_t)h * NE);
        const float4 b = *reinterpret_cast<const float4*>(Wg + (size_t)h * NE + 4);
        #pragma unroll
        for (int rr = 0; rr < 8; ++rr) {
            float* W = WgT + (size_t)rr * (NE * H_DIM);
            W[0 * H_DIM + h] = a.x;  W[1 * H_DIM + h] = a.y;
            W[2 * H_DIM + h] = a.z;  W[3 * H_DIM + h] = a.w;
            W[4 * H_DIM + h] = b.x;  W[5 * H_DIM + h] = b.y;
            W[6 * H_DIM + h] = b.z;  W[7 * H_DIM + h] = b.w;
        }
    }
}

// ---------------------------------------------------------------------------
// Prep W1: [E][H][HF] fp32 -> per-(e, f-quarter) k-slot-major bf16 images:
//   W1q[(e*4+fq)*32 + kstep][slot(8)][fl(128)][j(8)]  (16 KB per image)
// element k = kstep*64 + slot*8 + j, f = fq*128 + fl. Each image is exactly
// one expert-kernel A-stage (linear copy, conflict-free k-slot-major reads).
// ---------------------------------------------------------------------------
__global__ __launch_bounds__(256)
void prep_w1_kernel(const float* __restrict__ W1,
                    unsigned short* __restrict__ W1q)
{
    const int e     = blockIdx.x >> 5;
    const int kstep = blockIdx.x & 31;
    const int tid   = threadIdx.x;

    const float* src = W1 + ((size_t)e * H_DIM + kstep * BK) * HFD;

    #pragma unroll
    for (int slot = 0; slot < 8; ++slot) {
        #pragma unroll
        for (int half = 0; half < 2; ++half) {
            const int f  = half * 256 + tid;
            const int fq = f >> 7;
            const int fl = f & 127;
            float v[8];
            #pragma unroll
            for (int j = 0; j < 8; ++j)
                v[j] = src[(size_t)(slot * 8 + j) * HFD + f];   // lane-coalesced
            uint4 p;
            p.x = pack2(v[0], v[1]); p.y = pack2(v[2], v[3]);
            p.z = pack2(v[4], v[5]); p.w = pack2(v[6], v[7]);
            *reinterpret_cast<uint4*>(
                W1q + ((size_t)((e * 4 + fq) * 32 + kstep)) * 8192
                    + (slot * 128 + fl) * 8) = p;
        }
    }
}

// ---------------------------------------------------------------------------
// Gate logits: 256 blocks x 64 tokens; WgT staged once into LDS.
// Also converts x rows to bf16 (xb), which the expert kernel gathers.
// ---------------------------------------------------------------------------
__global__ __launch_bounds__(256)
void gate_logits_kernel(const float* __restrict__ x,
                        const float* __restrict__ WgT,
                        const float* __restrict__ bg,
                        float* __restrict__ out_logits,
                        float* __restrict__ wslot,
                        int*   __restrict__ route,
                        unsigned short* __restrict__ xb)
{
    __shared__ float Wlds[NE * H_DIM];   // 64 KB

    const int tid = threadIdx.x;
    const float* Wsrc = WgT + (size_t)(blockIdx.x & 7) * (NE * H_DIM);
    #pragma unroll
    for (int i = 0; i < (NE * H_DIM) / (256 * 4); ++i) {
        const int idx = (i * 256 + tid) * 4;
        *reinterpret_cast<float4*>(&Wlds[idx]) =
            *reinterpret_cast<const float4*>(Wsrc + idx);
    }
    __syncthreads();

    const int w = tid >> 6, l = tid & 63;
    const int tbase = blockIdx.x * 64 + w * 16;

    for (int pass = 0; pass < 4; ++pass) {
        const int t0 = tbase + pass * 4;
        float acc[4][NE];
        #pragma unroll
        for (int j = 0; j < 4; ++j)
            #pragma unroll
            for (int e = 0; e < NE; ++e) acc[j][e] = 0.f;

        for (int i = 0; i < 8; ++i) {
            const int h = i * 256 + 4 * l;
            float4 xv[4];
            #pragma unroll
            for (int j = 0; j < 4; ++j)
                xv[j] = *reinterpret_cast<const float4*>(
                    x + (size_t)(t0 + j) * H_DIM + h);
            #pragma unroll
            for (int j = 0; j < 4; ++j) {
                uint2 pk;
                pk.x = pack2(xv[j].x, xv[j].y);
                pk.y = pack2(xv[j].z, xv[j].w);
                *reinterpret_cast<uint2*>(xb + (size_t)(t0 + j) * H_DIM + h) = pk;
            }
            #pragma unroll
            for (int e = 0; e < NE; ++e) {
                const float4 wv = *reinterpret_cast<const float4*>(&Wlds[e * H_DIM + h]);
                #pragma unroll
                for (int j = 0; j < 4; ++j)
                    acc[j][e] += xv[j].x * wv.x + xv[j].y * wv.y
                               + xv[j].z * wv.z + xv[j].w * wv.w;
            }
        }

        #pragma unroll
        for (int j = 0; j < 4; ++j)
            #pragma unroll
            for (int e = 0; e < NE; ++e)
                #pragma unroll
                for (int off = 32; off > 0; off >>= 1)
                    acc[j][e] += __shfl_xor(acc[j][e], off, 64);

        if (l == 0) {
            #pragma unroll
            for (int j = 0; j < 4; ++j) {
                const int tok = t0 + j;
                float lg[NE];
                #pragma unroll
                for (int e = 0; e < NE; ++e) lg[e] = acc[j][e] + bg[e];

                float4* lo = reinterpret_cast<float4*>(out_logits + (size_t)tok * NE);
                lo[0] = make_float4(lg[0], lg[1], lg[2], lg[3]);
                lo[1] = make_float4(lg[4], lg[5], lg[6], lg[7]);

                int i0 = 0; float v0 = lg[0];
                #pragma unroll
                for (int e = 1; e < NE; ++e)
                    if (lg[e] > v0) { v0 = lg[e]; i0 = e; }
                int i1 = -1; float v1 = -3.4e38f;
                #pragma unroll
                for (int e = 0; e < NE; ++e)
                    if (e != i0 && lg[e] > v1) { v1 = lg[e]; i1 = e; }

                const float w0 = 1.f / (1.f + expf(v1 - v0));
                wslot[tok * 2]     = w0;
                wslot[tok * 2 + 1] = 1.f - w0;
                route[tok] = i0 | (i1 << 8);
            }
        }
    }
}

// ---------------------------------------------------------------------------
// Route/bucket: LDS-aggregated histogram; 8 global atomics per block.
// ---------------------------------------------------------------------------
__global__ __launch_bounds__(1024)
void route_kernel(const int* __restrict__ route,
                  int* __restrict__ counts,
                  int* __restrict__ bucket)
{
    __shared__ int lcnt[NE];
    __shared__ int lbase[NE];
    const int tid = threadIdx.x;
    const int tok = blockIdx.x * 1024 + tid;

    if (tid < NE) lcnt[tid] = 0;
    __syncthreads();

    const int rt = route[tok];
    const int i0 = rt & 255;
    const int i1 = rt >> 8;
    const int r0 = atomicAdd(&lcnt[i0], 1);
    const int r1 = atomicAdd(&lcnt[i1], 1);
    __syncthreads();

    if (tid < NE) lbase[tid] = atomicAdd(&counts[tid], lcnt[tid]);
    __syncthreads();

    bucket[i0 * B_TOK + lbase[i0] + r0] = tok * 2;
    bucket[i1 * B_TOK + lbase[i1] + r1] = tok * 2 + 1;
}

// ---------------------------------------------------------------------------
// Prefix: cbase[e] = row base; cpad[e] = count padded to 128.
// ---------------------------------------------------------------------------
__global__ void prefix_kernel(const int* __restrict__ counts,
                              int* __restrict__ cbase)
{
    if (threadIdx.x == 0 && blockIdx.x == 0) {
        int acc = 0;
        for (int e = 0; e < NE; ++e) {
            const int cp = ((counts[e] + 127) >> 7) << 7;
            cbase[e]      = acc;
            cbase[NE + e] = cp;
            acc += cp;
        }
    }
}

// ---------------------------------------------------------------------------
// invfill: inv[entry] = global P row for each bucket slot.
// ---------------------------------------------------------------------------
__global__ __launch_bounds__(256)
void invfill_kernel(const int* __restrict__ bucket,
                    const int* __restrict__ counts,
                    const int* __restrict__ cbase,
                    int* __restrict__ inv)
{
    const int e   = blockIdx.x & 7;
    const int pos = (blockIdx.x >> 3) * 256 + threadIdx.x;
    if (pos < counts[e]) inv[bucket[e * B_TOK + pos]] = cbase[e] + pos;
}

// ---------------------------------------------------------------------------
// Expert MFMA (m97-template): block = (e, f-quarter fq, 128-pos tile).
// 256 thr / 4 waves (2m x 2n), tile 128 f x 128 pos, BK=64, SINGLE-buffered
// 33 KB LDS -> 4 blocks/CU co-resident (the latency-hiding mechanism).
// Per K-step: stage A (linear gload_lds from prebaked k-slot image,
// conflict-free reads) + B (full-line row gather, source chunk pre-XORed
// so linear LDS dest + XORed read retrieves the right chunk) -> barrier ->
// 16 MFMA/wave -> barrier. Deterministic P4[fq] single-writer partials.
// ---------------------------------------------------------------------------
__global__ __launch_bounds__(256, 4)
void expert_mfma_kernel(const unsigned short* __restrict__ xb,
                        const unsigned short* __restrict__ W1q,
                        const float* __restrict__ b1,
                        const float* __restrict__ W2,
                        const int* __restrict__ counts,
                        const int* __restrict__ cbase,
                        const int* __restrict__ bucket,
                        float* __restrict__ P4)
{
    const int e  = blockIdx.x & 7;
    const int r  = blockIdx.x >> 3;
    const int fq = r & 3;
    const int pt = r >> 2;
    const int n  = counts[e];
    const int pos0 = pt * 128;
    if (pos0 >= n) return;
    const int nt = min(128, n - pos0);
    const int cb = cbase[e];

    __shared__ unsigned short Albs[8192];   // [slot8][fl128][j8]   16 KB
    __shared__ unsigned short Blds[8192];   // [pos128][chunk8^][8] 16 KB
    __shared__ float o_part[2][128];        // 1 KB

    const int tid = threadIdx.x;
    const int w   = tid >> 6;
    const int l   = tid & 63;
    const int lo5 = l & 31;
    const int hi  = l >> 5;
    const int wm  = w & 1;      // m half (64 f rows)
    const int wn  = w >> 1;     // n half (64 pos cols)

    const unsigned short* Aimg = W1q + (size_t)((e * 4 + fq) * 32) * 8192;

    // B gather bases: 4 (row, chunk') assignments per thread, source
    // pre-swizzled: stored chunk' holds source chunk (chunk' ^ (row&7)).
    const unsigned short* xsrc0, *xsrc1, *xsrc2, *xsrc3;
    {
        const int u0 = 0 * 256 + tid, u1 = 1 * 256 + tid,
                  u2 = 2 * 256 + tid, u3 = 3 * 256 + tid;
        const int r0 = u0 >> 3, r1 = u1 >> 3, r2 = u2 >> 3, r3 = u3 >> 3;
        const int t0 = bucket[e * B_TOK + min(pos0 + r0, n - 1)] >> 1;
        const int t1 = bucket[e * B_TOK + min(pos0 + r1, n - 1)] >> 1;
        const int t2 = bucket[e * B_TOK + min(pos0 + r2, n - 1)] >> 1;
        const int t3 = bucket[e * B_TOK + min(pos0 + r3, n - 1)] >> 1;
        xsrc0 = xb + (size_t)t0 * H_DIM + (((u0 & 7) ^ (r0 & 7)) * 8);
        xsrc1 = xb + (size_t)t1 * H_DIM + (((u1 & 7) ^ (r1 & 7)) * 8);
        xsrc2 = xb + (size_t)t2 * H_DIM + (((u2 & 7) ^ (r2 & 7)) * 8);
        xsrc3 = xb + (size_t)t3 * H_DIM + (((u3 & 7) ^ (r3 & 7)) * 8);
    }

    facc acc00, acc01, acc10, acc11;
    #pragma unroll
    for (int q = 0; q < 16; ++q) {
        acc00[q] = 0.f; acc01[q] = 0.f; acc10[q] = 0.f; acc11[q] = 0.f;
    }

    for (int kk = 0; kk < NKSTEP; ++kk) {
        // stage A: 16 KB linear copy (4 gload_lds16 per thread)
        const unsigned short* as = Aimg + (size_t)kk * 8192;
        {
            const int o0 = (0 * 256 + tid) * 8, o1 = (1 * 256 + tid) * 8;
            const int o2 = (2 * 256 + tid) * 8, o3 = (3 * 256 + tid) * 8;
            gload_lds16(as + o0, Albs + o0);
            gload_lds16(as + o1, Albs + o1);
            gload_lds16(as + o2, Albs + o2);
            gload_lds16(as + o3, Albs + o3);
            // stage B: full-line gather (4 per thread, pre-swizzled source)
            gload_lds16(xsrc0 + kk * BK, Blds + o0);
            gload_lds16(xsrc1 + kk * BK, Blds + o1);
            gload_lds16(xsrc2 + kk * BK, Blds + o2);
            gload_lds16(xsrc3 + kk * BK, Blds + o3);
        }
        __syncthreads();   // compiler drains vmcnt: tiles visible

        #pragma unroll
        for (int s = 0; s < 4; ++s) {
            const int slot  = s * 2 + hi;
            const int chunk = slot ^ (lo5 & 7);
            const bfrag a0 = *reinterpret_cast<const bfrag*>(
                &Albs[(slot * 128 + wm * 64 + lo5) * 8]);
            const bfrag a1 = *reinterpret_cast<const bfrag*>(
                &Albs[(slot * 128 + wm * 64 + 32 + lo5) * 8]);
            const bfrag b0 = *reinterpret_cast<const bfrag*>(
                &Blds[((wn * 64 + lo5) * 8 + chunk) * 8]);
            const bfrag b1v = *reinterpret_cast<const bfrag*>(
                &Blds[((wn * 64 + 32 + lo5) * 8 + chunk) * 8]);
            acc00 = __builtin_amdgcn_mfma_f32_32x32x16_bf16(a0, b0,  acc00, 0, 0, 0);
            acc01 = __builtin_amdgcn_mfma_f32_32x32x16_bf16(a0, b1v, acc01, 0, 0, 0);
            acc10 = __builtin_amdgcn_mfma_f32_32x32x16_bf16(a1, b0,  acc10, 0, 0, 0);
            acc11 = __builtin_amdgcn_mfma_f32_32x32x16_bf16(a1, b1v, acc11, 0, 0, 0);
        }
        __syncthreads();   // reads retired before next overwrite
    }

    // Epilogue: bias + exact GELU + W2 dot; reduce over this block's 128 f.
    const float* b1e = b1 + e * HFD + fq * 128;
    const float* W2e = W2 + e * HFD + fq * 128;
    const float kInvSqrt2 = 0.70710678118654752f;

    float po0 = 0.f, po1 = 0.f;
    #pragma unroll
    for (int mb = 0; mb < 2; ++mb) {
        const int base = wm * 64 + mb * 32 + 4 * hi;
        #pragma unroll
        for (int q = 0; q < 16; ++q) {
            const int frow = base + (q & 3) + 8 * (q >> 2);
            const float bv = b1e[frow];
            const float wv = W2e[frow];
            const float h0 = (mb ? acc10[q] : acc00[q]) + bv;
            const float h1 = (mb ? acc11[q] : acc01[q]) + bv;
            po0 += 0.5f * h0 * (1.f + erff(h0 * kInvSqrt2)) * wv;
            po1 += 0.5f * h1 * (1.f + erff(h1 * kInvSqrt2)) * wv;
        }
    }
    po0 += __shfl_xor(po0, 32, 64);
    po1 += __shfl_xor(po1, 32, 64);

    if (hi == 0) {
        o_part[wm][wn * 64 + lo5]      = po0;
        o_part[wm][wn * 64 + 32 + lo5] = po1;
    }
    __syncthreads();

    if (tid < nt)
        P4[(size_t)fq * PROWS + cb + pos0 + tid] =
            o_part[0][tid] + o_part[1][tid];
}

// ---------------------------------------------------------------------------
// Combine: out[t] = w0*Σ_fq P4[fq][g0] + w1*Σ_fq P4[fq][g1].
// Fixed summation order -> deterministic, no atomics anywhere.
// ---------------------------------------------------------------------------
__global__ __launch_bounds__(256)
void combine_kernel(const int* __restrict__ inv,
                    const float* __restrict__ P4,
                    const float* __restrict__ wslot,
                    float* __restrict__ out_scores)
{
    const int t = blockIdx.x * 256 + threadIdx.x;
    if (t >= B_TOK) return;
    const int g0 = inv[2 * t];
    const int g1 = inv[2 * t + 1];
    const float s0 = ((P4[g0] + P4[PROWS + g0]) + P4[2 * PROWS + g0])
                   + P4[3 * PROWS + g0];
    const float s1 = ((P4[g1] + P4[PROWS + g1]) + P4[2 * PROWS + g1])
                   + P4[3 * PROWS + g1];
    out_scores[t] = wslot[2 * t] * s0 + wslot[2 * t + 1] * s1;
}

// ---------------------------------------------------------------------------
extern "C" void kernel_launch(void* const* d_in, const int* in_sizes, int n_in,
                              void* d_out, int out_size, void* d_ws, size_t ws_size,
                              hipStream_t stream)
{
    const float* x  = (const float*)d_in[0];
    const float* W1 = (const float*)d_in[1];
    const float* b1 = (const float*)d_in[2];
    const float* W2 = (const float*)d_in[3];
    const float* Wg = (const float*)d_in[4];
    const float* bg = (const float*)d_in[5];

    float* out        = (float*)d_out;
    float* out_scores = out;            // [B, 1]
    float* out_logits = out + B_TOK;    // [B, E]

    char* ws = (char*)d_ws;
    int*            counts = (int*)           (ws + OFF_COUNTS);
    int*            cbase  = (int*)           (ws + OFF_CBASE);
    int*            bucket = (int*)           (ws + OFF_BUCKET);
    float*          wslot  = (float*)         (ws + OFF_WSLOT);
    int*            route  = (int*)           (ws + OFF_ROUTE);
    int*            inv    = (int*)           (ws + OFF_INV);
    float*          WgT    = (float*)         (ws + OFF_WGT);
    float*          P4     = (float*)         (ws + OFF_P4);
    unsigned short* W1q    = (unsigned short*)(ws + OFF_W1Q);
    unsigned short* xb     = (unsigned short*)(ws + OFF_XB);

    hipMemsetAsync(counts, 0, NE * sizeof(int), stream);

    wg_transpose_kernel<<<1, 256, 0, stream>>>(Wg, WgT);

    prep_w1_kernel<<<NE * NKSTEP, 256, 0, stream>>>(W1, W1q);

    gate_logits_kernel<<<B_TOK / 64, 256, 0, stream>>>(x, WgT, bg, out_logits,
                                                       wslot, route, xb);

    route_kernel<<<B_TOK / 1024, 1024, 0, stream>>>(route, counts, bucket);

    prefix_kernel<<<1, 64, 0, stream>>>(counts, cbase);

    invfill_kernel<<<NE * (B_TOK / 256), 256, 0, stream>>>(bucket, counts,
                                                           cbase, inv);

    expert_mfma_kernel<<<NE * 4 * PTMAX, 256, 0, stream>>>(
        xb, W1q, b1, W2, counts, cbase, bucket, P4);

    combine_kernel<<<B_TOK / 256, 256, 0, stream>>>(inv, P4, wslot, out_scores);
}